// Round 1
// baseline (1722.658 us; speedup 1.0000x reference)
//
#include <hip/hip_runtime.h>
#include <math.h>

#define NN 100000
#define EIN 800000
#define EEX 400000
#define ND 35
#define H 128
#define NG 256
#define NL 4
#define TM 16

__device__ __forceinline__ float silu_f(float x){ return x / (1.0f + expf(-x)); }

// ---------------- lin_node: h = silu(x @ W + b), 16 nodes/block ----------------
__global__ __launch_bounds__(256) void k_lin_node(const float* __restrict__ x,
                                                  const float* __restrict__ W,
                                                  const float* __restrict__ b,
                                                  float* __restrict__ h){
  __shared__ float Ws[ND*H];      // 17.5 KB
  __shared__ float xs[TM*ND];
  const int n0 = blockIdx.x * TM;
  for (int i = threadIdx.x; i < ND*H; i += 256) Ws[i] = W[i];
  for (int i = threadIdx.x; i < TM*ND; i += 256) xs[i] = x[(size_t)n0*ND + i];
  __syncthreads();
  const int j = threadIdx.x & (H-1);
  const int half = threadIdx.x >> 7;
  const float bj = b[j];
  #pragma unroll
  for (int r = 0; r < TM/2; ++r){
    const int m = half + 2*r;
    float acc = bj;
    #pragma unroll
    for (int k = 0; k < ND; ++k) acc += xs[m*ND + k] * Ws[k*H + j];
    h[(size_t)(n0+m)*H + j] = silu_f(acc);
  }
}

// ---------------- degree count ----------------
__global__ void k_count(const int* __restrict__ dst, int ne, int* __restrict__ cnt){
  int e = blockIdx.x*256 + threadIdx.x;
  if (e < ne) atomicAdd(&cnt[dst[e]], 1);
}

// ---------------- 2-level exclusive scan over N counts ----------------
__global__ void k_block_sum(const int* __restrict__ cnt, int n, int* __restrict__ bsum){
  __shared__ int s[256];
  int i = blockIdx.x*256 + threadIdx.x;
  s[threadIdx.x] = (i < n) ? cnt[i] : 0;
  __syncthreads();
  for (int o = 128; o > 0; o >>= 1){
    if (threadIdx.x < o) s[threadIdx.x] += s[threadIdx.x + o];
    __syncthreads();
  }
  if (threadIdx.x == 0) bsum[blockIdx.x] = s[0];
}
__global__ void k_scan_top(int* __restrict__ bsum, int nb){
  __shared__ int s[512];
  int t = threadIdx.x;
  int v = (t < nb) ? bsum[t] : 0;
  s[t] = v; __syncthreads();
  for (int o = 1; o < 512; o <<= 1){
    int a = (t >= o) ? s[t-o] : 0;
    __syncthreads();
    s[t] += a;
    __syncthreads();
  }
  if (t < nb) bsum[t] = s[t] - v;   // exclusive
}
__global__ void k_scan_write(const int* __restrict__ cnt, const int* __restrict__ bsum,
                             int n, int* __restrict__ rowp, int* __restrict__ cur){
  __shared__ int s[256];
  int t = threadIdx.x, i = blockIdx.x*256 + t;
  int v = (i < n) ? cnt[i] : 0;
  s[t] = v; __syncthreads();
  for (int o = 1; o < 256; o <<= 1){
    int a = (t >= o) ? s[t-o] : 0;
    __syncthreads();
    s[t] += a;
    __syncthreads();
  }
  if (i < n){
    int ex = bsum[blockIdx.x] + s[t] - v;
    rowp[i] = ex; cur[i] = ex;
  }
}

// ---------------- CSR fill ----------------
__global__ void k_fill_intra(const int* __restrict__ src, const int* __restrict__ dst,
                             const float* __restrict__ ea,
                             int* __restrict__ cur, int* __restrict__ col, float* __restrict__ val){
  int e = blockIdx.x*256 + threadIdx.x;
  if (e < EIN){
    int d = dst[e];
    int slot = atomicAdd(&cur[d], 1);
    col[slot] = src[e];
    val[slot] = ea[e];
  }
}
__global__ void k_fill_inter(const int* __restrict__ src, const int* __restrict__ dst,
                             const float* __restrict__ pos,
                             int* __restrict__ cur, int* __restrict__ col, float* __restrict__ val){
  int e = blockIdx.x*256 + threadIdx.x;
  if (e < EEX){
    int s = src[e], d = dst[e];
    float dx = pos[3*s+0] - pos[3*d+0];
    float dy = pos[3*s+1] - pos[3*d+1];
    float dz = pos[3*s+2] - pos[3*d+2];
    float w = expf(-(dx*dx + dy*dy + dz*dz));
    int slot = atomicAdd(&cur[d], 1);
    col[slot] = s;
    val[slot] = w;
  }
}

// ---------------- fused layer: gather -> matmul -> norm/silu/state update ----------------
__global__ __launch_bounds__(256) void k_layer(
    const float* __restrict__ hin, float* __restrict__ hout,
    float* __restrict__ vp, float* __restrict__ vl,
    const int* __restrict__ rowI, const int* __restrict__ cntI,
    const int* __restrict__ colI, const float* __restrict__ valI,
    const int* __restrict__ rowE, const int* __restrict__ cntE,
    const int* __restrict__ colE, const float* __restrict__ valE,
    const float* __restrict__ WI, const float* __restrict__ bI,
    const float* __restrict__ WE, const float* __restrict__ bE)
{
  __shared__ float aggI[TM][H];
  __shared__ float aggE[TM][H];
  const int n0 = blockIdx.x * TM;

  // ---- gather phase: threads = (j channel, half) ----
  {
    const int j = threadIdx.x & (H-1);
    const int half = threadIdx.x >> 7;
    for (int m = half; m < TM; m += 2){
      const int n = n0 + m;
      float aI = 0.f, aE = 0.f;
      int s = rowI[n], c = cntI[n];
      for (int t = 0; t < c; ++t){
        aI += hin[(size_t)colI[s+t]*H + j] * valI[s+t];
      }
      s = rowE[n]; c = cntE[n];
      for (int t = 0; t < c; ++t){
        aE += hin[(size_t)colE[s+t]*H + j] * valE[s+t];
      }
      aggI[m][j] = aI; aggE[m][j] = aE;
    }
  }
  __syncthreads();

  // ---- matmul phase: threads = (j0 in 0..63, q in 0..3); 4 nodes x 2 cols per thread ----
  const int j0 = threadIdx.x & 63;
  const int q  = threadIdx.x >> 6;   // wave-uniform
  float accI[4][2], accE[4][2];
  #pragma unroll
  for (int r = 0; r < 4; ++r){ accI[r][0]=accI[r][1]=accE[r][0]=accE[r][1]=0.f; }

  for (int kk = 0; kk < H; kk += 4){
    float aIb[4][4], aEb[4][4];
    #pragma unroll
    for (int r = 0; r < 4; ++r){
      const int m = q + 4*r;
      *(float4*)aIb[r] = *(const float4*)&aggI[m][kk];   // wave-uniform addr: LDS broadcast
      *(float4*)aEb[r] = *(const float4*)&aggE[m][kk];
    }
    #pragma unroll
    for (int k2 = 0; k2 < 4; ++k2){
      const int k = kk + k2;
      const float wi0 = WI[k*H + j0];
      const float wi1 = WI[k*H + j0 + 64];
      const float we0 = WE[k*H + j0];
      const float we1 = WE[k*H + j0 + 64];
      #pragma unroll
      for (int r = 0; r < 4; ++r){
        accI[r][0] += aIb[r][k2]*wi0;
        accI[r][1] += aIb[r][k2]*wi1;
        accE[r][0] += aEb[r][k2]*we0;
        accE[r][1] += aEb[r][k2]*we1;
      }
    }
  }

  // ---- epilogue ----
  #pragma unroll
  for (int r = 0; r < 4; ++r){
    const int m = q + 4*r;
    const int n = n0 + m;
    const float cI = (float)cntI[n];
    const float cE = (float)cntE[n];
    const float rdI = 1.0f / (cI + 1.0f);
    const float ldE = logf(cE + 1.0f);
    #pragma unroll
    for (int c2 = 0; c2 < 2; ++c2){
      const int j = j0 + 64*c2;
      const float mi = (accI[r][c2] + cI*bI[j]) * rdI;
      const float me = (accE[r][c2] + cE*bE[j]) * ldE;
      const size_t idx = (size_t)n*H + j;
      const float vpn = silu_f(mi + vp[idx]);
      const float vln = silu_f(me + vl[idx]);
      vp[idx] = vpn; vl[idx] = vln;
      hout[idx] = hin[idx] + vpn + vln;
    }
  }
}

// ---------------- pool: batch is sorted; register-accumulate, flush on boundary ----------------
__global__ void k_pool(const float* __restrict__ h, const int* __restrict__ batch,
                       float* __restrict__ g){
  const int j = threadIdx.x;
  const int n0 = blockIdx.x * 64;
  int nend = n0 + 64; if (nend > NN) nend = NN;
  float acc = 0.f;
  int cur = batch[n0];
  for (int n = n0; n < nend; ++n){
    int b = batch[n];
    if (b != cur){
      atomicAdd(&g[(size_t)cur*H + j], acc);
      acc = 0.f; cur = b;
    }
    acc += h[(size_t)n*H + j];
  }
  atomicAdd(&g[(size_t)cur*H + j], acc);
}

// ---------------- FC head: per-graph-row independent ----------------
__global__ void k_fc(const float* __restrict__ g, const float* __restrict__ fcW,
                     const float* __restrict__ fcb, const float* __restrict__ gamma,
                     const float* __restrict__ beta, const float* __restrict__ outW,
                     const float* __restrict__ outb, float* __restrict__ out){
  __shared__ float row[H];
  __shared__ float red[H];
  const int gi = blockIdx.x;
  const int j = threadIdx.x;
  row[j] = g[(size_t)gi*H + j];
  __syncthreads();
  const float bn_scale = rsqrtf(1.0f + 1e-5f);
  for (int l = 0; l < 3; ++l){
    const float* W = fcW + (size_t)l*H*H;
    float acc = fcb[l*H + j];
    #pragma unroll 8
    for (int k = 0; k < H; ++k) acc += row[k] * W[k*H + j];
    acc = (acc > 0.f) ? acc : 0.01f*acc;             // leaky_relu
    acc = acc * bn_scale * gamma[l*H + j] + beta[l*H + j];
    __syncthreads();
    row[j] = acc;
    __syncthreads();
  }
  red[j] = row[j] * outW[j];
  __syncthreads();
  for (int o = 64; o > 0; o >>= 1){
    if (j < o) red[j] += red[j + o];
    __syncthreads();
  }
  if (j == 0) out[gi] = red[0] + outb[0];
}

extern "C" void kernel_launch(void* const* d_in, const int* in_sizes, int n_in,
                              void* d_out, int out_size, void* d_ws, size_t ws_size,
                              hipStream_t stream)
{
  const float* x    = (const float*)d_in[0];
  const int*   eii  = (const int*)  d_in[1];
  const int*   eie  = (const int*)  d_in[2];
  const float* pos  = (const float*)d_in[3];
  const float* ea   = (const float*)d_in[4];
  const int*   batch= (const int*)  d_in[5];
  const float* lnW  = (const float*)d_in[6];
  const float* lnb  = (const float*)d_in[7];
  const float* WIa  = (const float*)d_in[8];
  const float* bIa  = (const float*)d_in[9];
  const float* WEa  = (const float*)d_in[10];
  const float* bEa  = (const float*)d_in[11];
  const float* fcW  = (const float*)d_in[12];
  const float* fcb  = (const float*)d_in[13];
  const float* gam  = (const float*)d_in[14];
  const float* bet  = (const float*)d_in[15];
  const float* outW = (const float*)d_in[16];
  const float* outb = (const float*)d_in[17];
  float* out = (float*)d_out;

  const int* src_i = eii;  const int* dst_i = eii + EIN;
  const int* src_e = eie;  const int* dst_e = eie + EEX;

  const size_t NH = (size_t)NN * H;
  float* hA = (float*)d_ws;
  float* hB = hA + NH;
  float* vp = hB + NH;
  float* vl = vp + NH;
  float* gp = vl + NH;                     // NG*H
  int* cnt_i = (int*)(gp + (size_t)NG*H);  // NN
  int* cnt_e = cnt_i + NN;
  int* row_i = cnt_e + NN;
  int* row_e = row_i + NN;
  int* cur_i = row_e + NN;
  int* cur_e = cur_i + NN;
  int* col_i = cur_e + NN;                 // EIN
  float* val_i = (float*)(col_i + EIN);    // EIN
  int* col_e = (int*)(val_i + EIN);        // EEX
  float* val_e = (float*)(col_e + EEX);    // EEX
  int* bsum = (int*)(val_e + EEX);         // 1024

  const size_t need = (4*NH + (size_t)NG*H + 6*(size_t)NN + 2*(size_t)EIN + 2*(size_t)EEX + 1024)*4;
  if (ws_size < need) return;  // workspace insufficient — fail loudly via wrong output

  // zero: vp+vl (contiguous), gp+cnt_i+cnt_e (contiguous)
  hipMemsetAsync(vp, 0, 2*NH*sizeof(float), stream);
  hipMemsetAsync(gp, 0, (size_t)NG*H*sizeof(float) + 2*(size_t)NN*sizeof(int), stream);

  k_lin_node<<<NN/TM, 256, 0, stream>>>(x, lnW, lnb, hA);

  k_count<<<(EIN+255)/256, 256, 0, stream>>>(dst_i, EIN, cnt_i);
  k_count<<<(EEX+255)/256, 256, 0, stream>>>(dst_e, EEX, cnt_e);

  const int NB = (NN + 255)/256;  // 391 <= 512
  k_block_sum<<<NB, 256, 0, stream>>>(cnt_i, NN, bsum);
  k_scan_top<<<1, 512, 0, stream>>>(bsum, NB);
  k_scan_write<<<NB, 256, 0, stream>>>(cnt_i, bsum, NN, row_i, cur_i);
  k_block_sum<<<NB, 256, 0, stream>>>(cnt_e, NN, bsum);
  k_scan_top<<<1, 512, 0, stream>>>(bsum, NB);
  k_scan_write<<<NB, 256, 0, stream>>>(cnt_e, bsum, NN, row_e, cur_e);

  k_fill_intra<<<(EIN+255)/256, 256, 0, stream>>>(src_i, dst_i, ea, cur_i, col_i, val_i);
  k_fill_inter<<<(EEX+255)/256, 256, 0, stream>>>(src_e, dst_e, pos, cur_e, col_e, val_e);

  const float* hin = hA; float* hout = hB;
  for (int l = 0; l < NL; ++l){
    k_layer<<<NN/TM, 256, 0, stream>>>(hin, hout, vp, vl,
        row_i, cnt_i, col_i, val_i,
        row_e, cnt_e, col_e, val_e,
        WIa + (size_t)l*H*H, bIa + (size_t)l*H,
        WEa + (size_t)l*H*H, bEa + (size_t)l*H);
    float* t = (float*)hin; hin = hout; hout = t;
  }
  // after 4 swaps final h is back in hA == hin

  k_pool<<<(NN+63)/64, H, 0, stream>>>(hin, batch, gp);
  k_fc<<<NG, H, 0, stream>>>(gp, fcW, fcb, gam, bet, outW, outb, out);
}

// Round 2
// 1412.048 us; speedup vs baseline: 1.2200x; 1.2200x over previous
//
#include <hip/hip_runtime.h>
#include <math.h>

#define NN 100000
#define EIN 800000
#define EEX 400000
#define ND 35
#define H 128
#define NG 256
#define NL 4
#define TM 8           // nodes per block in k_layer
#define TML 16         // nodes per block in k_lin_node

__device__ __forceinline__ float silu_f(float x){ return x / (1.0f + expf(-x)); }

// ---------------- lin_node: h = silu(x @ W + b), 16 nodes/block ----------------
__global__ __launch_bounds__(256) void k_lin_node(const float* __restrict__ x,
                                                  const float* __restrict__ W,
                                                  const float* __restrict__ b,
                                                  float* __restrict__ h){
  __shared__ float Ws[ND*H];      // 17.5 KB
  __shared__ float xs[TML*ND];
  const int n0 = blockIdx.x * TML;
  for (int i = threadIdx.x; i < ND*H; i += 256) Ws[i] = W[i];
  for (int i = threadIdx.x; i < TML*ND; i += 256) xs[i] = x[(size_t)n0*ND + i];
  __syncthreads();
  const int j = threadIdx.x & (H-1);
  const int half = threadIdx.x >> 7;
  const float bj = b[j];
  #pragma unroll
  for (int r = 0; r < TML/2; ++r){
    const int m = half + 2*r;
    float acc = bj;
    #pragma unroll
    for (int k = 0; k < ND; ++k) acc += xs[m*ND + k] * Ws[k*H + j];
    h[(size_t)(n0+m)*H + j] = silu_f(acc);
  }
}

// ---------------- degree count ----------------
__global__ void k_count(const int* __restrict__ dst, int ne, int* __restrict__ cnt){
  int e = blockIdx.x*256 + threadIdx.x;
  if (e < ne) atomicAdd(&cnt[dst[e]], 1);
}

// ---------------- 2-level exclusive scan over N counts ----------------
__global__ void k_block_sum(const int* __restrict__ cnt, int n, int* __restrict__ bsum){
  __shared__ int s[256];
  int i = blockIdx.x*256 + threadIdx.x;
  s[threadIdx.x] = (i < n) ? cnt[i] : 0;
  __syncthreads();
  for (int o = 128; o > 0; o >>= 1){
    if (threadIdx.x < o) s[threadIdx.x] += s[threadIdx.x + o];
    __syncthreads();
  }
  if (threadIdx.x == 0) bsum[blockIdx.x] = s[0];
}
__global__ void k_scan_top(int* __restrict__ bsum, int nb){
  __shared__ int s[512];
  int t = threadIdx.x;
  int v = (t < nb) ? bsum[t] : 0;
  s[t] = v; __syncthreads();
  for (int o = 1; o < 512; o <<= 1){
    int a = (t >= o) ? s[t-o] : 0;
    __syncthreads();
    s[t] += a;
    __syncthreads();
  }
  if (t < nb) bsum[t] = s[t] - v;   // exclusive
}
__global__ void k_scan_write(const int* __restrict__ cnt, const int* __restrict__ bsum,
                             int n, int* __restrict__ rowp, int* __restrict__ cur){
  __shared__ int s[256];
  int t = threadIdx.x, i = blockIdx.x*256 + t;
  int v = (i < n) ? cnt[i] : 0;
  s[t] = v; __syncthreads();
  for (int o = 1; o < 256; o <<= 1){
    int a = (t >= o) ? s[t-o] : 0;
    __syncthreads();
    s[t] += a;
    __syncthreads();
  }
  if (i < n){
    int ex = bsum[blockIdx.x] + s[t] - v;
    rowp[i] = ex; cur[i] = ex;
  }
}

// ---------------- CSR fill ----------------
__global__ void k_fill_intra(const int* __restrict__ src, const int* __restrict__ dst,
                             const float* __restrict__ ea,
                             int* __restrict__ cur, int* __restrict__ col, float* __restrict__ val){
  int e = blockIdx.x*256 + threadIdx.x;
  if (e < EIN){
    int d = dst[e];
    int slot = atomicAdd(&cur[d], 1);
    col[slot] = src[e];
    val[slot] = ea[e];
  }
}
__global__ void k_fill_inter(const int* __restrict__ src, const int* __restrict__ dst,
                             const float* __restrict__ pos,
                             int* __restrict__ cur, int* __restrict__ col, float* __restrict__ val){
  int e = blockIdx.x*256 + threadIdx.x;
  if (e < EEX){
    int s = src[e], d = dst[e];
    float dx = pos[3*s+0] - pos[3*d+0];
    float dy = pos[3*s+1] - pos[3*d+1];
    float dz = pos[3*s+2] - pos[3*d+2];
    float w = expf(-(dx*dx + dy*dy + dz*dz));
    int slot = atomicAdd(&cur[d], 1);
    col[slot] = s;
    val[slot] = w;
  }
}

// ---------------- fused layer: gather -> matmul -> norm/silu/state update ----------------
// Gather: thread = (slot 0..7, lane 0..31); 1 node/thread, float4 channels,
// 2-way unrolled edge loop -> ~12-edge dependent chain instead of ~96.
__global__ __launch_bounds__(256) void k_layer(
    const float* __restrict__ hin, float* __restrict__ hout,
    float* __restrict__ vp, float* __restrict__ vl,
    const int* __restrict__ rowI, const int* __restrict__ cntI,
    const int* __restrict__ colI, const float* __restrict__ valI,
    const int* __restrict__ rowE, const int* __restrict__ cntE,
    const int* __restrict__ colE, const float* __restrict__ valE,
    const float* __restrict__ WI, const float* __restrict__ bI,
    const float* __restrict__ WE, const float* __restrict__ bE)
{
  __shared__ float aggI[TM][H];
  __shared__ float aggE[TM][H];
  const int n0 = blockIdx.x * TM;

  // ---- gather phase ----
  {
    const int slot = threadIdx.x >> 5;          // 0..7 -> node
    const int lane = threadIdx.x & 31;          // 0..31 -> float4 channel group
    const int j4 = lane * 4;
    const int n = n0 + slot;

    float ax=0.f, ay=0.f, az=0.f, aw=0.f;
    {
      const int s = rowI[n], c = cntI[n];
      int t = 0;
      for (; t + 2 <= c; t += 2){
        const int c0 = colI[s+t];
        const int c1 = colI[s+t+1];
        const float v0 = valI[s+t];
        const float v1 = valI[s+t+1];
        const float4 h0 = *(const float4*)(hin + (size_t)c0*H + j4);
        const float4 h1 = *(const float4*)(hin + (size_t)c1*H + j4);
        ax += h0.x*v0 + h1.x*v1;
        ay += h0.y*v0 + h1.y*v1;
        az += h0.z*v0 + h1.z*v1;
        aw += h0.w*v0 + h1.w*v1;
      }
      if (t < c){
        const int c0 = colI[s+t];
        const float v0 = valI[s+t];
        const float4 h0 = *(const float4*)(hin + (size_t)c0*H + j4);
        ax += h0.x*v0; ay += h0.y*v0; az += h0.z*v0; aw += h0.w*v0;
      }
      aggI[slot][j4+0] = ax; aggI[slot][j4+1] = ay;
      aggI[slot][j4+2] = az; aggI[slot][j4+3] = aw;
    }
    ax=0.f; ay=0.f; az=0.f; aw=0.f;
    {
      const int s = rowE[n], c = cntE[n];
      int t = 0;
      for (; t + 2 <= c; t += 2){
        const int c0 = colE[s+t];
        const int c1 = colE[s+t+1];
        const float v0 = valE[s+t];
        const float v1 = valE[s+t+1];
        const float4 h0 = *(const float4*)(hin + (size_t)c0*H + j4);
        const float4 h1 = *(const float4*)(hin + (size_t)c1*H + j4);
        ax += h0.x*v0 + h1.x*v1;
        ay += h0.y*v0 + h1.y*v1;
        az += h0.z*v0 + h1.z*v1;
        aw += h0.w*v0 + h1.w*v1;
      }
      if (t < c){
        const int c0 = colE[s+t];
        const float v0 = valE[s+t];
        const float4 h0 = *(const float4*)(hin + (size_t)c0*H + j4);
        ax += h0.x*v0; ay += h0.y*v0; az += h0.z*v0; aw += h0.w*v0;
      }
      aggE[slot][j4+0] = ax; aggE[slot][j4+1] = ay;
      aggE[slot][j4+2] = az; aggE[slot][j4+3] = aw;
    }
  }
  __syncthreads();

  // ---- matmul phase: thread = (j0 0..63, q 0..3); 2 nodes x 2 cols per thread ----
  const int j0 = threadIdx.x & 63;
  const int q  = threadIdx.x >> 6;   // wave-uniform
  float accI[2][2], accE[2][2];
  #pragma unroll
  for (int r = 0; r < 2; ++r){ accI[r][0]=accI[r][1]=accE[r][0]=accE[r][1]=0.f; }

  for (int kk = 0; kk < H; kk += 4){
    float aIb[2][4], aEb[2][4];
    #pragma unroll
    for (int r = 0; r < 2; ++r){
      const int m = q + 4*r;
      *(float4*)aIb[r] = *(const float4*)&aggI[m][kk];   // wave-uniform addr: LDS broadcast
      *(float4*)aEb[r] = *(const float4*)&aggE[m][kk];
    }
    #pragma unroll
    for (int k2 = 0; k2 < 4; ++k2){
      const int k = kk + k2;
      const float wi0 = WI[k*H + j0];
      const float wi1 = WI[k*H + j0 + 64];
      const float we0 = WE[k*H + j0];
      const float we1 = WE[k*H + j0 + 64];
      #pragma unroll
      for (int r = 0; r < 2; ++r){
        accI[r][0] += aIb[r][k2]*wi0;
        accI[r][1] += aIb[r][k2]*wi1;
        accE[r][0] += aEb[r][k2]*we0;
        accE[r][1] += aEb[r][k2]*we1;
      }
    }
  }

  // ---- epilogue ----
  #pragma unroll
  for (int r = 0; r < 2; ++r){
    const int m = q + 4*r;
    const int n = n0 + m;
    const float cI = (float)cntI[n];
    const float cE = (float)cntE[n];
    const float rdI = 1.0f / (cI + 1.0f);
    const float ldE = logf(cE + 1.0f);
    #pragma unroll
    for (int c2 = 0; c2 < 2; ++c2){
      const int j = j0 + 64*c2;
      const float mi = (accI[r][c2] + cI*bI[j]) * rdI;
      const float me = (accE[r][c2] + cE*bE[j]) * ldE;
      const size_t idx = (size_t)n*H + j;
      const float vpn = silu_f(mi + vp[idx]);
      const float vln = silu_f(me + vl[idx]);
      vp[idx] = vpn; vl[idx] = vln;
      hout[idx] = hin[idx] + vpn + vln;
    }
  }
}

// ---------------- pool: batch is sorted; register-accumulate, flush on boundary ----------------
__global__ void k_pool(const float* __restrict__ h, const int* __restrict__ batch,
                       float* __restrict__ g){
  const int j = threadIdx.x;
  const int n0 = blockIdx.x * 64;
  int nend = n0 + 64; if (nend > NN) nend = NN;
  float acc = 0.f;
  int cur = batch[n0];
  for (int n = n0; n < nend; ++n){
    int b = batch[n];
    if (b != cur){
      atomicAdd(&g[(size_t)cur*H + j], acc);
      acc = 0.f; cur = b;
    }
    acc += h[(size_t)n*H + j];
  }
  atomicAdd(&g[(size_t)cur*H + j], acc);
}

// ---------------- FC head: per-graph-row independent ----------------
__global__ void k_fc(const float* __restrict__ g, const float* __restrict__ fcW,
                     const float* __restrict__ fcb, const float* __restrict__ gamma,
                     const float* __restrict__ beta, const float* __restrict__ outW,
                     const float* __restrict__ outb, float* __restrict__ out){
  __shared__ float row[H];
  __shared__ float red[H];
  const int gi = blockIdx.x;
  const int j = threadIdx.x;
  row[j] = g[(size_t)gi*H + j];
  __syncthreads();
  const float bn_scale = rsqrtf(1.0f + 1e-5f);
  for (int l = 0; l < 3; ++l){
    const float* W = fcW + (size_t)l*H*H;
    float acc = fcb[l*H + j];
    #pragma unroll 8
    for (int k = 0; k < H; ++k) acc += row[k] * W[k*H + j];
    acc = (acc > 0.f) ? acc : 0.01f*acc;             // leaky_relu
    acc = acc * bn_scale * gamma[l*H + j] + beta[l*H + j];
    __syncthreads();
    row[j] = acc;
    __syncthreads();
  }
  red[j] = row[j] * outW[j];
  __syncthreads();
  for (int o = 64; o > 0; o >>= 1){
    if (j < o) red[j] += red[j + o];
    __syncthreads();
  }
  if (j == 0) out[gi] = red[0] + outb[0];
}

extern "C" void kernel_launch(void* const* d_in, const int* in_sizes, int n_in,
                              void* d_out, int out_size, void* d_ws, size_t ws_size,
                              hipStream_t stream)
{
  const float* x    = (const float*)d_in[0];
  const int*   eii  = (const int*)  d_in[1];
  const int*   eie  = (const int*)  d_in[2];
  const float* pos  = (const float*)d_in[3];
  const float* ea   = (const float*)d_in[4];
  const int*   batch= (const int*)  d_in[5];
  const float* lnW  = (const float*)d_in[6];
  const float* lnb  = (const float*)d_in[7];
  const float* WIa  = (const float*)d_in[8];
  const float* bIa  = (const float*)d_in[9];
  const float* WEa  = (const float*)d_in[10];
  const float* bEa  = (const float*)d_in[11];
  const float* fcW  = (const float*)d_in[12];
  const float* fcb  = (const float*)d_in[13];
  const float* gam  = (const float*)d_in[14];
  const float* bet  = (const float*)d_in[15];
  const float* outW = (const float*)d_in[16];
  const float* outb = (const float*)d_in[17];
  float* out = (float*)d_out;

  const int* src_i = eii;  const int* dst_i = eii + EIN;
  const int* src_e = eie;  const int* dst_e = eie + EEX;

  const size_t NH = (size_t)NN * H;
  float* hA = (float*)d_ws;
  float* hB = hA + NH;
  float* vp = hB + NH;
  float* vl = vp + NH;
  float* gp = vl + NH;                     // NG*H
  int* cnt_i = (int*)(gp + (size_t)NG*H);  // NN
  int* cnt_e = cnt_i + NN;
  int* row_i = cnt_e + NN;
  int* row_e = row_i + NN;
  int* cur_i = row_e + NN;
  int* cur_e = cur_i + NN;
  int* col_i = cur_e + NN;                 // EIN
  float* val_i = (float*)(col_i + EIN);    // EIN
  int* col_e = (int*)(val_i + EIN);        // EEX
  float* val_e = (float*)(col_e + EEX);    // EEX
  int* bsum = (int*)(val_e + EEX);         // 1024

  const size_t need = (4*NH + (size_t)NG*H + 6*(size_t)NN + 2*(size_t)EIN + 2*(size_t)EEX + 1024)*4;
  if (ws_size < need) return;

  // zero: vp+vl (contiguous), gp+cnt_i+cnt_e (contiguous)
  hipMemsetAsync(vp, 0, 2*NH*sizeof(float), stream);
  hipMemsetAsync(gp, 0, (size_t)NG*H*sizeof(float) + 2*(size_t)NN*sizeof(int), stream);

  k_lin_node<<<NN/TML, 256, 0, stream>>>(x, lnW, lnb, hA);

  k_count<<<(EIN+255)/256, 256, 0, stream>>>(dst_i, EIN, cnt_i);
  k_count<<<(EEX+255)/256, 256, 0, stream>>>(dst_e, EEX, cnt_e);

  const int NB = (NN + 255)/256;  // 391 <= 512
  k_block_sum<<<NB, 256, 0, stream>>>(cnt_i, NN, bsum);
  k_scan_top<<<1, 512, 0, stream>>>(bsum, NB);
  k_scan_write<<<NB, 256, 0, stream>>>(cnt_i, bsum, NN, row_i, cur_i);
  k_block_sum<<<NB, 256, 0, stream>>>(cnt_e, NN, bsum);
  k_scan_top<<<1, 512, 0, stream>>>(bsum, NB);
  k_scan_write<<<NB, 256, 0, stream>>>(cnt_e, bsum, NN, row_e, cur_e);

  k_fill_intra<<<(EIN+255)/256, 256, 0, stream>>>(src_i, dst_i, ea, cur_i, col_i, val_i);
  k_fill_inter<<<(EEX+255)/256, 256, 0, stream>>>(src_e, dst_e, pos, cur_e, col_e, val_e);

  const float* hin = hA; float* hout = hB;
  for (int l = 0; l < NL; ++l){
    k_layer<<<NN/TM, 256, 0, stream>>>(hin, hout, vp, vl,
        row_i, cnt_i, col_i, val_i,
        row_e, cnt_e, col_e, val_e,
        WIa + (size_t)l*H*H, bIa + (size_t)l*H,
        WEa + (size_t)l*H*H, bEa + (size_t)l*H);
    float* t = (float*)hin; hin = hout; hout = t;
  }
  // after 4 swaps final h is back in hA == hin

  k_pool<<<(NN+63)/64, H, 0, stream>>>(hin, batch, gp);
  k_fc<<<NG, H, 0, stream>>>(gp, fcW, fcb, gam, bet, outW, outb, out);
}